// Round 11
// baseline (100.035 us; speedup 1.0000x reference)
//
#include <hip/hip_runtime.h>

#define BS 8192
#define D  128
#define TI 128              // i-rows per block (2 waves x 64)
#define JCHUNK 256          // j's per block chunk
#define NJC (BS / JCHUNK)   // 32 (grid.y)
#define NP 8                // panels per chunk (32 j-rows = 8 KB each)

#define AS1 __attribute__((address_space(1)))
#define AS3 __attribute__((address_space(3)))

typedef __bf16 bf16x8 __attribute__((ext_vector_type(8)));
typedef float  f32x16 __attribute__((ext_vector_type(16)));

// ---------------------------------------------------------------------------
// pack: feats -> fragment-major bf16 for BOTH anchor (Apack) and positive
// (Ppack), plus the fp32 row reductions (a_sq, p_sq, pd2). Layout (verified
// R6-R10): piece ((tile*8 + s)*64 + lane) holds the 8 bf16 operand elements
// for MFMA lane `lane` at k-step s of 32-row tile `tile`:
//   row = tile*32 + (lane&31), k = s*16 + (lane>>5)*8 .. +8
// ---------------------------------------------------------------------------
__global__ __launch_bounds__(256) void pack_kernel(
        const float* __restrict__ feats,
        __bf16* __restrict__ Apack, __bf16* __restrict__ Ppack,
        float* __restrict__ a_sq, float* __restrict__ p_sq,
        float* __restrict__ pd2)
{
    const int tile = blockIdx.x;          // 0..255
    const int tid  = threadIdx.x;
    const int r    = tid >> 3;            // row within tile, 0..31
    const int kb   = tid & 7;             // k-block = MFMA step s, 0..7
    const int row  = tile * 32 + r;

    const float4* asrc = (const float4*)(feats + (size_t)row * D + kb * 16);
    const float4* psrc = (const float4*)(feats + (size_t)(row + BS) * D + kb * 16);
    float4 a0 = asrc[0], a1 = asrc[1], a2 = asrc[2], a3 = asrc[3];
    float4 p0 = psrc[0], p1 = psrc[1], p2 = psrc[2], p3 = psrc[3];

    bf16x8 alo, ahi, plo, phi;
    alo[0]=(__bf16)a0.x; alo[1]=(__bf16)a0.y; alo[2]=(__bf16)a0.z; alo[3]=(__bf16)a0.w;
    alo[4]=(__bf16)a1.x; alo[5]=(__bf16)a1.y; alo[6]=(__bf16)a1.z; alo[7]=(__bf16)a1.w;
    ahi[0]=(__bf16)a2.x; ahi[1]=(__bf16)a2.y; ahi[2]=(__bf16)a2.z; ahi[3]=(__bf16)a2.w;
    ahi[4]=(__bf16)a3.x; ahi[5]=(__bf16)a3.y; ahi[6]=(__bf16)a3.z; ahi[7]=(__bf16)a3.w;
    plo[0]=(__bf16)p0.x; plo[1]=(__bf16)p0.y; plo[2]=(__bf16)p0.z; plo[3]=(__bf16)p0.w;
    plo[4]=(__bf16)p1.x; plo[5]=(__bf16)p1.y; plo[6]=(__bf16)p1.z; plo[7]=(__bf16)p1.w;
    phi[0]=(__bf16)p2.x; phi[1]=(__bf16)p2.y; phi[2]=(__bf16)p2.z; phi[3]=(__bf16)p2.w;
    phi[4]=(__bf16)p3.x; phi[5]=(__bf16)p3.y; phi[6]=(__bf16)p3.z; phi[7]=(__bf16)p3.w;

    const size_t pb = ((size_t)tile * 8 + kb) * 64;
    ((bf16x8*)Apack)[pb + r]      = alo;
    ((bf16x8*)Apack)[pb + 32 + r] = ahi;
    ((bf16x8*)Ppack)[pb + r]      = plo;
    ((bf16x8*)Ppack)[pb + 32 + r] = phi;

    float sa = a0.x*a0.x + a0.y*a0.y + a0.z*a0.z + a0.w*a0.w
             + a1.x*a1.x + a1.y*a1.y + a1.z*a1.z + a1.w*a1.w
             + a2.x*a2.x + a2.y*a2.y + a2.z*a2.z + a2.w*a2.w
             + a3.x*a3.x + a3.y*a3.y + a3.z*a3.z + a3.w*a3.w;
    float sp = p0.x*p0.x + p0.y*p0.y + p0.z*p0.z + p0.w*p0.w
             + p1.x*p1.x + p1.y*p1.y + p1.z*p1.z + p1.w*p1.w
             + p2.x*p2.x + p2.y*p2.y + p2.z*p2.z + p2.w*p2.w
             + p3.x*p3.x + p3.y*p3.y + p3.z*p3.z + p3.w*p3.w;
    float d;
    float sd = 0.0f;
    d = a0.x-p0.x; sd += d*d;  d = a0.y-p0.y; sd += d*d;
    d = a0.z-p0.z; sd += d*d;  d = a0.w-p0.w; sd += d*d;
    d = a1.x-p1.x; sd += d*d;  d = a1.y-p1.y; sd += d*d;
    d = a1.z-p1.z; sd += d*d;  d = a1.w-p1.w; sd += d*d;
    d = a2.x-p2.x; sd += d*d;  d = a2.y-p2.y; sd += d*d;
    d = a2.z-p2.z; sd += d*d;  d = a2.w-p2.w; sd += d*d;
    d = a3.x-p3.x; sd += d*d;  d = a3.y-p3.y; sd += d*d;
    d = a3.z-p3.z; sd += d*d;  d = a3.w-p3.w; sd += d*d;

    #pragma unroll
    for (int off = 1; off <= 4; off <<= 1) {
        sa += __shfl_xor(sa, off, 64);
        sp += __shfl_xor(sp, off, 64);
        sd += __shfl_xor(sd, off, 64);
    }
    if (kb == 0) { a_sq[row] = sa; p_sq[row] = sp; pd2[row] = sd; }
}

// ---------------------------------------------------------------------------
// max kernel: 2-wave blocks (128 thr), 128 i-rows x 256 j-chunk. The two
// waves SHARE one 2 x 8 KB LDS double buffer (16 KB/block), so per-wave LDS
// footprint is 8 KB and launch_bounds(128,3) gives 3 blocks/CU = 12 waves/CU
// (vs the 8 waves/CU that R8/R9/R10 were all stuck at). VGPR footprint ~155
// fits the 170 budget with no spill (R7's spill was a ~190 footprint at 170).
// B streams as 8 panels (32 j-rows = 8 KB) via global_load_lds DMA, each
// wave staging half a panel (wave-uniform base + lane*16). Barrier per panel;
// the panel t+1 DMAs issued at the top of iteration t are long done by the
// barrier's vmcnt(0), so the drain is cheap.
//
// acc initialized to -p_sq[col]/2 (cinit[8]), so after the K-loop
// acc = cross - p_sq/2 and min_j d2 = a_sq - 2*max acc -> one v_max per reg.
//
// mfma_f32_32x32x16_bf16 C/D layout (HW-verified, learn_hip m74/m101):
//   col = lane&31, row = (reg&3) + 8*(reg>>2) + 4*(lane>>5)
// ---------------------------------------------------------------------------
__global__ __launch_bounds__(128, 3) void max_kernel(
        const __bf16* __restrict__ Apack, const __bf16* __restrict__ Ppack,
        const float* __restrict__ p_sq, float* __restrict__ partmax)
{
    __shared__ __bf16 smem[2 * 4096];           // 2 x 8 KB panel buffers

    const int tid  = threadIdx.x;               // 0..127
    const int wave = tid >> 6;                  // 0 or 1
    const int lane = tid & 63;
    const int l31  = lane & 31;
    const int half = lane >> 5;

    const int i0    = blockIdx.x * TI + wave * 64;    // wave's 64 anchor rows
    const int itile = i0 >> 5;
    const int jbase = blockIdx.y * JCHUNK;
    const int tile0 = jbase >> 5;

    // A fragments (2 tiles), coalesced 1 KB wave-loads from Apack
    bf16x8 afA[8], afB[8];
    {
        const bf16x8* ap = (const bf16x8*)Apack;
        #pragma unroll
        for (int s = 0; s < 8; ++s) {
            afA[s] = ap[((size_t)itile * 8 + s) * 64 + lane];
            afB[s] = ap[((size_t)(itile + 1) * 8 + s) * 64 + lane];
        }
    }

    // preload panel constants: cinit[t] = -p_sq[jbase + t*32 + l31]/2
    float cinit[NP];
    #pragma unroll
    for (int t = 0; t < NP; ++t)
        cinit[t] = -0.5f * p_sq[jbase + t * 32 + l31];

    float rmaxA[16], rmaxB[16];
    #pragma unroll
    for (int r = 0; r < 16; ++r) { rmaxA[r] = -3.0e38f; rmaxB[r] = -3.0e38f; }

    // panel piece stream: panel p = pieces gp[p*512 + s*64 + lane], s=0..7
    const bf16x8* gp = (const bf16x8*)Ppack + (size_t)tile0 * 512;
    const bf16x8* sm = (const bf16x8*)smem;

    // DMA one 8 KB panel into buffer (p&1): 512 pieces, 4 per thread.
    // piece index = p*512 + h*128 + wave*64 + lane; LDS dest = uniform base
    // (h*128 + wave*64)*16 + lane*16 — exact global_load_lds form.
    #define STAGE(p)                                                         \
        {                                                                    \
            const bf16x8* gb = gp + (size_t)(p) * 512 + wave * 64 + lane;    \
            char* lb = (char*)smem + ((p) & 1) * 8192 + wave * 64 * 16;      \
            _Pragma("unroll")                                                \
            for (int h = 0; h < 4; ++h)                                      \
                __builtin_amdgcn_global_load_lds(                            \
                    (AS1 void*)(gb + h * 128),                               \
                    (AS3 void*)(lb + h * 128 * 16), 16, 0, 0);               \
        }

    STAGE(0)
    __syncthreads();

    #pragma unroll 2
    for (int t = 0; t < NP; ++t) {
        if (t + 1 < NP) STAGE(t + 1)

        const bf16x8* buf = sm + (t & 1) * 512;
        const float ci = cinit[t];
        f32x16 acc0, acc1;
        #pragma unroll
        for (int r = 0; r < 16; ++r) { acc0[r] = ci; acc1[r] = ci; }
        #pragma unroll
        for (int s = 0; s < 8; ++s) {
            bf16x8 b = buf[s * 64 + lane];
            acc0 = __builtin_amdgcn_mfma_f32_32x32x16_bf16(afA[s], b, acc0,
                                                           0, 0, 0);
            acc1 = __builtin_amdgcn_mfma_f32_32x32x16_bf16(afB[s], b, acc1,
                                                           0, 0, 0);
        }
        #pragma unroll
        for (int r = 0; r < 16; ++r) {
            rmaxA[r] = fmaxf(rmaxA[r], acc0[r]);
            rmaxB[r] = fmaxf(rmaxB[r], acc1[r]);
        }

        if (t + 1 < NP) __syncthreads();
    }
    #undef STAGE

    // max across the 32 columns (lanes sharing the same half)
    #pragma unroll
    for (int r = 0; r < 16; ++r) {
        float vA = rmaxA[r], vB = rmaxB[r];
        #pragma unroll
        for (int off = 1; off <= 16; off <<= 1) {
            vA = fmaxf(vA, __shfl_xor(vA, off, 64));
            vB = fmaxf(vB, __shfl_xor(vB, off, 64));
        }
        rmaxA[r] = vA; rmaxB[r] = vB;
    }
    if (l31 == 0) {
        float* dst = partmax + (size_t)blockIdx.y * BS + i0;
        #pragma unroll
        for (int r = 0; r < 16; ++r) {
            int row = (r & 3) + 8 * (r >> 2) + 4 * half;
            dst[row]      = rmaxA[r];
            dst[row + 32] = rmaxB[r];
        }
    }
}

// ---------------------------------------------------------------------------
// fin stage 1: 32 blocks x 256 threads; thread handles exactly one i.
// min_j d2 = a_sq[i] - 2 * max_c partmax[c][i]
// ---------------------------------------------------------------------------
__global__ __launch_bounds__(256) void fin1_kernel(
        const float* __restrict__ partmax, const float* __restrict__ a_sq,
        const float* __restrict__ pd2, float* __restrict__ bsum)
{
    __shared__ float ssum[4];
    const int t = threadIdx.x;
    const int i = blockIdx.x * 256 + t;

    float m = -3.0e38f;
    #pragma unroll
    for (int c = 0; c < NJC; ++c)
        m = fmaxf(m, partmax[c * BS + i]);
    float negd = sqrtf(fmaxf(fmaf(-2.0f, m, a_sq[i]), 0.0f));
    float posd = sqrtf(pd2[i]);
    float sum = fmaxf(posd - negd + 1.0f, 0.0f);

    #pragma unroll
    for (int off = 32; off >= 1; off >>= 1) sum += __shfl_xor(sum, off, 64);
    if ((t & 63) == 0) ssum[t >> 6] = sum;
    __syncthreads();
    if (t == 0)
        bsum[blockIdx.x] = ssum[0] + ssum[1] + ssum[2] + ssum[3];
}

// fin stage 2: one wave sums the 32 block partials.
__global__ __launch_bounds__(64) void fin2_kernel(
        const float* __restrict__ bsum, float* __restrict__ out)
{
    const int t = threadIdx.x;
    float v = (t < 32) ? bsum[t] : 0.0f;
    #pragma unroll
    for (int off = 32; off >= 1; off >>= 1) v += __shfl_xor(v, off, 64);
    if (t == 0) out[0] = v / (float)BS;
}

// ---------------------------------------------------------------------------
extern "C" void kernel_launch(void* const* d_in, const int* in_sizes, int n_in,
                              void* d_out, int out_size, void* d_ws,
                              size_t ws_size, hipStream_t stream)
{
    const float* feats = (const float*)d_in[0];

    char* ws = (char*)d_ws;
    __bf16* Apack = (__bf16*)ws;  ws += (size_t)BS * D * 2;   // 2 MB
    __bf16* Ppack = (__bf16*)ws;  ws += (size_t)BS * D * 2;   // 2 MB
    float* a_sq   = (float*)ws;   ws += (size_t)BS * 4;
    float* p_sq   = (float*)ws;   ws += (size_t)BS * 4;
    float* pd2    = (float*)ws;   ws += (size_t)BS * 4;
    float* partmax = (float*)ws;  ws += (size_t)NJC * BS * 4; // 1 MB
    float* bsum   = (float*)ws;   ws += 32 * 4;

    pack_kernel<<<BS / 32, 256, 0, stream>>>(feats, Apack, Ppack,
                                             a_sq, p_sq, pd2);
    dim3 grid(BS / TI, NJC);
    max_kernel<<<grid, 128, 0, stream>>>(Apack, Ppack, p_sq, partmax);
    fin1_kernel<<<BS / 256, 256, 0, stream>>>(partmax, a_sq, pd2, bsum);
    fin2_kernel<<<1, 64, 0, stream>>>(bsum, (float*)d_out);
}

// Round 12
// 81.993 us; speedup vs baseline: 1.2200x; 1.2200x over previous
//
#include <hip/hip_runtime.h>

#define BS 8192
#define D  128
#define TI 128              // i-rows per block (2 waves x 64)
#define JCHUNK 512          // j's per block chunk
#define NJC (BS / JCHUNK)   // 16 (grid.y)
#define NP 16               // panels per chunk (32 j-rows each)

typedef __bf16 bf16x8 __attribute__((ext_vector_type(8)));
typedef float  f32x16 __attribute__((ext_vector_type(16)));

// ---------------------------------------------------------------------------
// pack: feats -> fragment-major bf16 for BOTH anchor (Apack) and positive
// (Ppack), plus the fp32 row reductions (a_sq, p_sq, pd2). Layout (verified
// R6-R11): piece ((tile*8 + s)*64 + lane) holds the 8 bf16 operand elements
// for MFMA lane `lane` at k-step s of 32-row tile `tile`:
//   row = tile*32 + (lane&31), k = s*16 + (lane>>5)*8 .. +8
// ---------------------------------------------------------------------------
__global__ __launch_bounds__(256) void pack_kernel(
        const float* __restrict__ feats,
        __bf16* __restrict__ Apack, __bf16* __restrict__ Ppack,
        float* __restrict__ a_sq, float* __restrict__ p_sq,
        float* __restrict__ pd2)
{
    const int tile = blockIdx.x;          // 0..255
    const int tid  = threadIdx.x;
    const int r    = tid >> 3;            // row within tile, 0..31
    const int kb   = tid & 7;             // k-block = MFMA step s, 0..7
    const int row  = tile * 32 + r;

    const float4* asrc = (const float4*)(feats + (size_t)row * D + kb * 16);
    const float4* psrc = (const float4*)(feats + (size_t)(row + BS) * D + kb * 16);
    float4 a0 = asrc[0], a1 = asrc[1], a2 = asrc[2], a3 = asrc[3];
    float4 p0 = psrc[0], p1 = psrc[1], p2 = psrc[2], p3 = psrc[3];

    bf16x8 alo, ahi, plo, phi;
    alo[0]=(__bf16)a0.x; alo[1]=(__bf16)a0.y; alo[2]=(__bf16)a0.z; alo[3]=(__bf16)a0.w;
    alo[4]=(__bf16)a1.x; alo[5]=(__bf16)a1.y; alo[6]=(__bf16)a1.z; alo[7]=(__bf16)a1.w;
    ahi[0]=(__bf16)a2.x; ahi[1]=(__bf16)a2.y; ahi[2]=(__bf16)a2.z; ahi[3]=(__bf16)a2.w;
    ahi[4]=(__bf16)a3.x; ahi[5]=(__bf16)a3.y; ahi[6]=(__bf16)a3.z; ahi[7]=(__bf16)a3.w;
    plo[0]=(__bf16)p0.x; plo[1]=(__bf16)p0.y; plo[2]=(__bf16)p0.z; plo[3]=(__bf16)p0.w;
    plo[4]=(__bf16)p1.x; plo[5]=(__bf16)p1.y; plo[6]=(__bf16)p1.z; plo[7]=(__bf16)p1.w;
    phi[0]=(__bf16)p2.x; phi[1]=(__bf16)p2.y; phi[2]=(__bf16)p2.z; phi[3]=(__bf16)p2.w;
    phi[4]=(__bf16)p3.x; phi[5]=(__bf16)p3.y; phi[6]=(__bf16)p3.z; phi[7]=(__bf16)p3.w;

    const size_t pb = ((size_t)tile * 8 + kb) * 64;
    ((bf16x8*)Apack)[pb + r]      = alo;
    ((bf16x8*)Apack)[pb + 32 + r] = ahi;
    ((bf16x8*)Ppack)[pb + r]      = plo;
    ((bf16x8*)Ppack)[pb + 32 + r] = phi;

    float sa = a0.x*a0.x + a0.y*a0.y + a0.z*a0.z + a0.w*a0.w
             + a1.x*a1.x + a1.y*a1.y + a1.z*a1.z + a1.w*a1.w
             + a2.x*a2.x + a2.y*a2.y + a2.z*a2.z + a2.w*a2.w
             + a3.x*a3.x + a3.y*a3.y + a3.z*a3.z + a3.w*a3.w;
    float sp = p0.x*p0.x + p0.y*p0.y + p0.z*p0.z + p0.w*p0.w
             + p1.x*p1.x + p1.y*p1.y + p1.z*p1.z + p1.w*p1.w
             + p2.x*p2.x + p2.y*p2.y + p2.z*p2.z + p2.w*p2.w
             + p3.x*p3.x + p3.y*p3.y + p3.z*p3.z + p3.w*p3.w;
    float d;
    float sd = 0.0f;
    d = a0.x-p0.x; sd += d*d;  d = a0.y-p0.y; sd += d*d;
    d = a0.z-p0.z; sd += d*d;  d = a0.w-p0.w; sd += d*d;
    d = a1.x-p1.x; sd += d*d;  d = a1.y-p1.y; sd += d*d;
    d = a1.z-p1.z; sd += d*d;  d = a1.w-p1.w; sd += d*d;
    d = a2.x-p2.x; sd += d*d;  d = a2.y-p2.y; sd += d*d;
    d = a2.z-p2.z; sd += d*d;  d = a2.w-p2.w; sd += d*d;
    d = a3.x-p3.x; sd += d*d;  d = a3.y-p3.y; sd += d*d;
    d = a3.z-p3.z; sd += d*d;  d = a3.w-p3.w; sd += d*d;

    #pragma unroll
    for (int off = 1; off <= 4; off <<= 1) {
        sa += __shfl_xor(sa, off, 64);
        sp += __shfl_xor(sp, off, 64);
        sd += __shfl_xor(sd, off, 64);
    }
    if (kb == 0) { a_sq[row] = sa; p_sq[row] = sp; pd2[row] = sd; }
}

// ---------------------------------------------------------------------------
// max kernel: NO LDS, NO BARRIERS — registers-only B pipeline.
// 2-wave blocks (128 thr), 128 i-rows x 512 j-chunk; each wave owns 64 rows
// (two A-fragment sets, register-resident all kernel). B streams as 16
// panels (32 j-rows) DOUBLE-BUFFERED IN REGISTERS: panel t+1's 8 coalesced
// 1 KB global loads issue before panel t's MFMAs. Register loads get EXACT
// per-register vmcnt tracking from the compiler (unlike LDS consumption,
// which forces a conservative vmcnt(0) drain every panel — the ~30 us
// plateau of R5/R8/R9/R10). Both waves read the same B addresses -> wave 1
// hits L1, halving L2 traffic. All 1024 blocks resident in one round
// (4 blocks/CU at launch_bounds(128,2); ~212 VGPR < 256, no spill).
//
// acc initialized to -p_sq[col]/2, so after the K-loop acc = cross - p_sq/2
// and min_j d2 = a_sq - 2*max acc -> one v_max per reg.
//
// mfma_f32_32x32x16_bf16 C/D layout (HW-verified, learn_hip m74/m101):
//   col = lane&31, row = (reg&3) + 8*(reg>>2) + 4*(lane>>5)
// ---------------------------------------------------------------------------
__global__ __launch_bounds__(128, 2) void max_kernel(
        const __bf16* __restrict__ Apack, const __bf16* __restrict__ Ppack,
        const float* __restrict__ p_sq, float* __restrict__ partmax)
{
    const int tid  = threadIdx.x;               // 0..127
    const int wave = tid >> 6;                  // 0 or 1
    const int lane = tid & 63;
    const int l31  = lane & 31;
    const int half = lane >> 5;

    const int i0    = blockIdx.x * TI + wave * 64;    // wave's 64 anchor rows
    const int itile = i0 >> 5;
    const int jbase = blockIdx.y * JCHUNK;
    const int tile0 = jbase >> 5;

    // A fragments (2 tiles), coalesced 1 KB wave-loads from Apack
    bf16x8 afA[8], afB[8];
    {
        const bf16x8* ap = (const bf16x8*)Apack;
        #pragma unroll
        for (int s = 0; s < 8; ++s) {
            afA[s] = ap[((size_t)itile * 8 + s) * 64 + lane];
            afB[s] = ap[((size_t)(itile + 1) * 8 + s) * 64 + lane];
        }
    }

    float rmaxA[16], rmaxB[16];
    #pragma unroll
    for (int r = 0; r < 16; ++r) { rmaxA[r] = -3.0e38f; rmaxB[r] = -3.0e38f; }

    // panel piece stream: panel p = pieces gp[p*512 + s*64], lane-offset
    const bf16x8* gp = (const bf16x8*)Ppack + (size_t)tile0 * 512 + lane;

    // register double buffer: prologue loads panel 0
    bf16x8 bcur[8], bnxt[8];
    #pragma unroll
    for (int s = 0; s < 8; ++s) bcur[s] = gp[s * 64];
    float cicur = -0.5f * p_sq[jbase + l31];
    float cinxt = 0.0f;

    #pragma unroll
    for (int t = 0; t < NP; ++t) {
        if (t + 1 < NP) {
            // prefetch panel t+1 into registers (exact vmcnt, stays in
            // flight across panel t's MFMAs)
            #pragma unroll
            for (int s = 0; s < 8; ++s) bnxt[s] = gp[(t + 1) * 512 + s * 64];
            cinxt = -0.5f * p_sq[jbase + (t + 1) * 32 + l31];
        }

        f32x16 acc0, acc1;
        #pragma unroll
        for (int r = 0; r < 16; ++r) { acc0[r] = cicur; acc1[r] = cicur; }
        #pragma unroll
        for (int s = 0; s < 8; ++s) {
            acc0 = __builtin_amdgcn_mfma_f32_32x32x16_bf16(afA[s], bcur[s],
                                                           acc0, 0, 0, 0);
            acc1 = __builtin_amdgcn_mfma_f32_32x32x16_bf16(afB[s], bcur[s],
                                                           acc1, 0, 0, 0);
        }
        #pragma unroll
        for (int r = 0; r < 16; ++r) {
            rmaxA[r] = fmaxf(rmaxA[r], acc0[r]);
            rmaxB[r] = fmaxf(rmaxB[r], acc1[r]);
        }

        if (t + 1 < NP) {
            #pragma unroll
            for (int s = 0; s < 8; ++s) bcur[s] = bnxt[s];  // renamed away
            cicur = cinxt;
        }
    }

    // max across the 32 columns (lanes sharing the same half)
    #pragma unroll
    for (int r = 0; r < 16; ++r) {
        float vA = rmaxA[r], vB = rmaxB[r];
        #pragma unroll
        for (int off = 1; off <= 16; off <<= 1) {
            vA = fmaxf(vA, __shfl_xor(vA, off, 64));
            vB = fmaxf(vB, __shfl_xor(vB, off, 64));
        }
        rmaxA[r] = vA; rmaxB[r] = vB;
    }
    if (l31 == 0) {
        float* dst = partmax + (size_t)blockIdx.y * BS + i0;
        #pragma unroll
        for (int r = 0; r < 16; ++r) {
            int row = (r & 3) + 8 * (r >> 2) + 4 * half;
            dst[row]      = rmaxA[r];
            dst[row + 32] = rmaxB[r];
        }
    }
}

// ---------------------------------------------------------------------------
// fin stage 1: 32 blocks x 256 threads; thread handles exactly one i.
// min_j d2 = a_sq[i] - 2 * max_c partmax[c][i]
// ---------------------------------------------------------------------------
__global__ __launch_bounds__(256) void fin1_kernel(
        const float* __restrict__ partmax, const float* __restrict__ a_sq,
        const float* __restrict__ pd2, float* __restrict__ bsum)
{
    __shared__ float ssum[4];
    const int t = threadIdx.x;
    const int i = blockIdx.x * 256 + t;

    float m = -3.0e38f;
    #pragma unroll
    for (int c = 0; c < NJC; ++c)
        m = fmaxf(m, partmax[c * BS + i]);
    float negd = sqrtf(fmaxf(fmaf(-2.0f, m, a_sq[i]), 0.0f));
    float posd = sqrtf(pd2[i]);
    float sum = fmaxf(posd - negd + 1.0f, 0.0f);

    #pragma unroll
    for (int off = 32; off >= 1; off >>= 1) sum += __shfl_xor(sum, off, 64);
    if ((t & 63) == 0) ssum[t >> 6] = sum;
    __syncthreads();
    if (t == 0)
        bsum[blockIdx.x] = ssum[0] + ssum[1] + ssum[2] + ssum[3];
}

// fin stage 2: one wave sums the 32 block partials.
__global__ __launch_bounds__(64) void fin2_kernel(
        const float* __restrict__ bsum, float* __restrict__ out)
{
    const int t = threadIdx.x;
    float v = (t < 32) ? bsum[t] : 0.0f;
    #pragma unroll
    for (int off = 32; off >= 1; off >>= 1) v += __shfl_xor(v, off, 64);
    if (t == 0) out[0] = v / (float)BS;
}

// ---------------------------------------------------------------------------
extern "C" void kernel_launch(void* const* d_in, const int* in_sizes, int n_in,
                              void* d_out, int out_size, void* d_ws,
                              size_t ws_size, hipStream_t stream)
{
    const float* feats = (const float*)d_in[0];

    char* ws = (char*)d_ws;
    __bf16* Apack = (__bf16*)ws;  ws += (size_t)BS * D * 2;   // 2 MB
    __bf16* Ppack = (__bf16*)ws;  ws += (size_t)BS * D * 2;   // 2 MB
    float* a_sq   = (float*)ws;   ws += (size_t)BS * 4;
    float* p_sq   = (float*)ws;   ws += (size_t)BS * 4;
    float* pd2    = (float*)ws;   ws += (size_t)BS * 4;
    float* partmax = (float*)ws;  ws += (size_t)NJC * BS * 4; // 512 KB
    float* bsum   = (float*)ws;   ws += 32 * 4;

    pack_kernel<<<BS / 32, 256, 0, stream>>>(feats, Apack, Ppack,
                                             a_sq, p_sq, pd2);
    dim3 grid(BS / TI, NJC);
    max_kernel<<<grid, 128, 0, stream>>>(Apack, Ppack, p_sq, partmax);
    fin1_kernel<<<BS / 256, 256, 0, stream>>>(partmax, a_sq, pd2, bsum);
    fin2_kernel<<<1, 64, 0, stream>>>(bsum, (float*)d_out);
}